// Round 5
// baseline (327.933 us; speedup 1.0000x reference)
//
#include <hip/hip_runtime.h>
#include <hip/hip_bf16.h>

typedef short short8 __attribute__((ext_vector_type(8)));
typedef float floatx4 __attribute__((ext_vector_type(4)));

constexpr int BATCH = 8, SEQ = 2048, DIMC = 512, HID = 1024, QKD = 128, NHID = 2176;
constexpr int TOK = BATCH * SEQ;

// workspace layout (bytes)
constexpr size_t OFF_XN  = 0;
constexpr size_t OFF_WHT = OFF_XN  + (size_t)TOK * DIMC * 2;
constexpr size_t OFF_WOT = OFF_WHT + (size_t)NHID * DIMC * 2;
constexpr size_t OFF_UV  = OFF_WOT + (size_t)DIMC * HID * 2;
constexpr size_t OFF_Q   = OFF_UV  + (size_t)TOK * NHID * 2;
constexpr size_t OFF_K   = OFF_Q   + (size_t)TOK * QKD * 2;
constexpr size_t OFF_VT  = OFF_K   + (size_t)TOK * QKD * 2;
constexpr size_t OFF_P   = OFF_VT  + (size_t)BATCH * HID * SEQ * 2;
constexpr size_t OFF_HU  = OFF_P   + (size_t)BATCH * SEQ * SEQ * 2;

__device__ inline void gload_lds16(const __hip_bfloat16* g, __hip_bfloat16* l) {
    __builtin_amdgcn_global_load_lds(
        (const __attribute__((address_space(1))) void*)g,
        (__attribute__((address_space(3))) void*)l, 16, 0, 0);
}

// ---------------- LayerNorm ----------------
__global__ __launch_bounds__(256) void ln_kernel(const float* __restrict__ x,
                                                 const float* __restrict__ w,
                                                 const float* __restrict__ b,
                                                 __hip_bfloat16* __restrict__ xn) {
    int t = blockIdx.x;
    const float* xr = x + (size_t)t * DIMC;
    float2 v = ((const float2*)xr)[threadIdx.x];
    float s = v.x + v.y;
    float ss = v.x * v.x + v.y * v.y;
    for (int o = 32; o; o >>= 1) { s += __shfl_down(s, o); ss += __shfl_down(ss, o); }
    __shared__ float red[8];
    int wid = threadIdx.x >> 6, lane = threadIdx.x & 63;
    if (lane == 0) { red[wid] = s; red[4 + wid] = ss; }
    __syncthreads();
    if (threadIdx.x == 0) {
        float a = red[0] + red[1] + red[2] + red[3];
        float q = red[4] + red[5] + red[6] + red[7];
        float mu = a * (1.0f / DIMC);
        red[0] = mu;
        red[4] = q * (1.0f / DIMC) - mu * mu;
    }
    __syncthreads();
    float mu = red[0];
    float inv = rsqrtf(red[4] + 1e-5f);
    int c = threadIdx.x * 2;
    float y0 = (v.x - mu) * inv * w[c] + b[c];
    float y1 = (v.y - mu) * inv * w[c + 1] + b[c + 1];
    __hip_bfloat16* o = xn + (size_t)t * DIMC + c;
    o[0] = __float2bfloat16(y0);
    o[1] = __float2bfloat16(y1);
}

// ------------- weight convert+transpose -------------
__global__ __launch_bounds__(256) void cvt_kernel(const float* __restrict__ Wh,
                                                  const float* __restrict__ Wo,
                                                  __hip_bfloat16* __restrict__ WhT,
                                                  __hip_bfloat16* __restrict__ WoT) {
    int i = blockIdx.x * 256 + threadIdx.x;
    const int total1 = NHID * DIMC;
    const int total2 = DIMC * HID;
    if (i < total1) {
        int n = i / DIMC, k = i % DIMC;
        WhT[i] = __float2bfloat16(Wh[(size_t)k * NHID + n]);
    } else if (i < total1 + total2) {
        int j = i - total1;
        int d = j / HID, h = j % HID;
        WoT[j] = __float2bfloat16(Wo[(size_t)h * DIMC + d]);
    }
}

// ------------- q/k rotary + key-mask-zero -------------
__global__ __launch_bounds__(256) void qkrot_kernel(const __hip_bfloat16* __restrict__ uv,
                                                    const float* __restrict__ sn,
                                                    const float* __restrict__ cs,
                                                    const int* __restrict__ mask,
                                                    const float* __restrict__ gamma,
                                                    const float* __restrict__ beta,
                                                    __hip_bfloat16* __restrict__ q,
                                                    __hip_bfloat16* __restrict__ k) {
    int t = blockIdx.x * 4 + (threadIdx.x >> 6);
    int j = threadIdx.x & 63;
    const __hip_bfloat16* base = uv + (size_t)t * NHID + 2 * HID;
    float b0 = __bfloat162float(base[2 * j]);
    float b1 = __bfloat162float(base[2 * j + 1]);
    float q0 = b0 * gamma[2 * j] + beta[2 * j];
    float q1 = b1 * gamma[2 * j + 1] + beta[2 * j + 1];
    float k0 = b0 * gamma[QKD + 2 * j] + beta[QKD + 2 * j];
    float k1 = b1 * gamma[QKD + 2 * j + 1] + beta[QKD + 2 * j + 1];
    float s = sn[(size_t)t * 64 + j];
    float c = cs[(size_t)t * 64 + j];
    int bb = t >> 11, nn = t & (SEQ - 1);
    float km = (mask[(size_t)bb * SEQ + nn] != 0) ? 0.f : 1.f;
    q[(size_t)t * QKD + j]       = __float2bfloat16(q0 * c - q1 * s);
    q[(size_t)t * QKD + 64 + j]  = __float2bfloat16(q1 * c + q0 * s);
    k[(size_t)t * QKD + j]       = __float2bfloat16((k0 * c - k1 * s) * km);
    k[(size_t)t * QKD + 64 + j]  = __float2bfloat16((k1 * c + k0 * s) * km);
}

// ------------- V transpose -------------
__global__ __launch_bounds__(256) void vt_kernel(const __hip_bfloat16* __restrict__ uv,
                                                 __hip_bfloat16* __restrict__ Vt) {
    __shared__ __hip_bfloat16 tile[64][65];
    int n0 = blockIdx.x * 64, h0 = blockIdx.y * 64, b = blockIdx.z;
    #pragma unroll
    for (int i = 0; i < 16; i++) {
        int idx = i * 256 + threadIdx.x;
        int r = idx >> 6, c = idx & 63;
        tile[r][c] = uv[((size_t)(b * SEQ + n0 + r)) * NHID + HID + h0 + c];
    }
    __syncthreads();
    #pragma unroll
    for (int i = 0; i < 16; i++) {
        int idx = i * 256 + threadIdx.x;
        int r = idx >> 6, c = idx & 63;
        Vt[((size_t)b * HID + h0 + r) * SEQ + n0 + c] = tile[c][r];
    }
}

// ============ m97-structure GEMM + swizzled global_load_lds staging ============
// C[M][N] = A[M][K] @ Bt[N][K]^T. 128x128 tile, BK=64, 4 waves (2x2 of 64x64).
// LDS 32KB (linear [128][64] per operand) -> ~3 blocks/CU; stalls covered by
// cross-block wave overlap (m114). Swizzle both-sides: stage source chunk
// (l&7)^(l>>3), read chunk kc^(row&7)  [involution; conflicts==0 proven R3/R4].
// EPI 0: silu(acc+bias)->bf16 | 1: relu^2/32768->bf16 | 2: acc*U->bf16
// EPI 3: acc+bias+Xres->f32
template <int EPI>
__global__ __launch_bounds__(256) void gemm_m97(
    const __hip_bfloat16* __restrict__ A, int lda, long long sA,
    const __hip_bfloat16* __restrict__ Bt, int ldb, long long sB,
    int K,
    const float* __restrict__ bias,
    const __hip_bfloat16* __restrict__ U, int ldu, long long sU,
    const float* __restrict__ Xres, int ldx,
    __hip_bfloat16* __restrict__ Cb, float* __restrict__ Cf, int ldc, long long sC) {
    __shared__ __hip_bfloat16 As[128 * 64];
    __shared__ __hip_bfloat16 Bs[128 * 64];

    if (sA) A += (size_t)blockIdx.z * sA;
    if (sB) Bt += (size_t)blockIdx.z * sB;
    if (sC) { if (Cb) Cb += (size_t)blockIdx.z * sC; if (Cf) Cf += (size_t)blockIdx.z * sC; }
    if (U && sU) U += (size_t)blockIdx.z * sU;

    // bijective XCD swizzle on xy-linear block id (all grids have nwg%8==0)
    int nwg = gridDim.x * gridDim.y;
    int lin = blockIdx.x + gridDim.x * blockIdx.y;
    int bid = (lin & 7) * (nwg >> 3) + (lin >> 3);
    int m0 = (bid % gridDim.x) * 128;
    int n0 = (bid / gridDim.x) * 128;

    int tid = threadIdx.x, lane = tid & 63, wid = tid >> 6;
    int wr = (wid >> 1) * 64, wc = (wid & 1) * 64;

    floatx4 acc[4][4] = {};

    // staging: wave covers 32 rows (4 x 8-row groups); lane l -> row +(l>>3),
    // LDS chunk (l&7); pre-swizzled global chunk (l&7)^(l>>3)
    int rb = wid * 32;
    int srow = lane >> 3;
    int sch = ((lane & 7) ^ (lane >> 3)) * 8;

    // LDS slot (row,c) holds global chunk c^(row&7)
    #define FRAG(P, row, kc) (*(const short8*)&(P)[(row) * 64 + (((kc) ^ ((row) & 7)) << 3)])

    for (int kt = 0; kt < K; kt += 64) {
        #pragma unroll
        for (int i = 0; i < 4; i++) {
            int r = rb + i * 8;                     // wave-uniform, multiple of 8
            gload_lds16(&A[(size_t)(m0 + r + srow) * lda + kt + sch], &As[r * 64]);
            gload_lds16(&Bt[(size_t)(n0 + r + srow) * ldb + kt + sch], &Bs[r * 64]);
        }
        __syncthreads();
        int rr = lane & 15;
        #pragma unroll
        for (int ko = 0; ko < 2; ko++) {
            short8 a[4], b[4];
            int kc = ko * 4 + (lane >> 4);          // chunk index 0..7
            #pragma unroll
            for (int m = 0; m < 4; m++) a[m] = FRAG(As, wr + m * 16 + rr, kc);
            #pragma unroll
            for (int n = 0; n < 4; n++) b[n] = FRAG(Bs, wc + n * 16 + rr, kc);
            #pragma unroll
            for (int m = 0; m < 4; m++)
                #pragma unroll
                for (int n = 0; n < 4; n++)
                    acc[m][n] = __builtin_amdgcn_mfma_f32_16x16x32_bf16(a[m], b[n], acc[m][n], 0, 0, 0);
        }
        __syncthreads();
    }
    #undef FRAG

    // epilogue: frag row=(lane>>4)*4+i, col=lane&15
    int r4 = (lane >> 4) * 4, cc = lane & 15;
    #pragma unroll
    for (int m = 0; m < 4; m++) {
        #pragma unroll
        for (int n = 0; n < 4; n++) {
            #pragma unroll
            for (int i = 0; i < 4; i++) {
                int row = m0 + wr + m * 16 + r4 + i;
                int col = n0 + wc + n * 16 + cc;
                float v = acc[m][n][i];
                if (EPI == 0) {
                    v += bias[col];
                    v = v / (1.0f + __expf(-v));
                    Cb[(size_t)row * ldc + col] = __float2bfloat16(v);
                } else if (EPI == 1) {
                    v = v > 0.0f ? v * v * (1.0f / 32768.0f) : 0.0f;
                    Cb[(size_t)row * ldc + col] = __float2bfloat16(v);
                } else if (EPI == 2) {
                    v *= __bfloat162float(U[(size_t)row * ldu + col]);
                    Cb[(size_t)row * ldc + col] = __float2bfloat16(v);
                } else {
                    v += bias[col] + Xres[(size_t)row * ldx + col];
                    Cf[(size_t)row * ldc + col] = v;
                }
            }
        }
    }
}

extern "C" void kernel_launch(void* const* d_in, const int* in_sizes, int n_in,
                              void* d_out, int out_size, void* d_ws, size_t ws_size,
                              hipStream_t stream) {
    const float* x     = (const float*)d_in[0];
    const float* msin  = (const float*)d_in[1];
    const float* mcos  = (const float*)d_in[2];
    const int*   mask  = (const int*)d_in[3];
    const float* lnw   = (const float*)d_in[4];
    const float* lnb   = (const float*)d_in[5];
    const float* Wh    = (const float*)d_in[6];
    const float* bh    = (const float*)d_in[7];
    const float* gamma = (const float*)d_in[8];
    const float* beta  = (const float*)d_in[9];
    const float* Wo    = (const float*)d_in[10];
    const float* bo    = (const float*)d_in[11];
    float* out = (float*)d_out;
    char* ws = (char*)d_ws;

    __hip_bfloat16* xn  = (__hip_bfloat16*)(ws + OFF_XN);
    __hip_bfloat16* WhT = (__hip_bfloat16*)(ws + OFF_WHT);
    __hip_bfloat16* WoT = (__hip_bfloat16*)(ws + OFF_WOT);
    __hip_bfloat16* uv  = (__hip_bfloat16*)(ws + OFF_UV);
    __hip_bfloat16* q   = (__hip_bfloat16*)(ws + OFF_Q);
    __hip_bfloat16* k   = (__hip_bfloat16*)(ws + OFF_K);
    __hip_bfloat16* Vt  = (__hip_bfloat16*)(ws + OFF_VT);
    __hip_bfloat16* P   = (__hip_bfloat16*)(ws + OFF_P);
    __hip_bfloat16* hu  = (__hip_bfloat16*)(ws + OFF_HU);

    // 1. LayerNorm -> xn (bf16)
    ln_kernel<<<TOK, 256, 0, stream>>>(x, lnw, lnb, xn);

    // 2. weight transpose/convert
    cvt_kernel<<<(NHID * DIMC + DIMC * HID + 255) / 256, 256, 0, stream>>>(Wh, Wo, WhT, WoT);

    // 3. GEMM1: uv = silu(xn @ Wh + bh)   [16384 x 2176 x 512]
    gemm_m97<0><<<dim3(TOK / 128, NHID / 128, 1), 256, 0, stream>>>(
        xn, DIMC, 0, WhT, DIMC, 0, DIMC, bh,
        nullptr, 0, 0, nullptr, 0, uv, nullptr, NHID, 0);

    // 4. q/k rotary, masked keys zeroed
    qkrot_kernel<<<TOK / 4, 256, 0, stream>>>(uv, msin, mcos, mask, gamma, beta, q, k);

    // 5. V transpose per batch
    vt_kernel<<<dim3(SEQ / 64, HID / 64, BATCH), 256, 0, stream>>>(uv, Vt);

    // 6. P = relu(q @ k^T)^2 / 32768   per batch [2048 x 2048 x 128]
    gemm_m97<1><<<dim3(SEQ / 128, SEQ / 128, BATCH), 256, 0, stream>>>(
        q, QKD, (long long)SEQ * QKD, k, QKD, (long long)SEQ * QKD, QKD, nullptr,
        nullptr, 0, 0, nullptr, 0, P, nullptr, SEQ, (long long)SEQ * SEQ);

    // 7. hu = (P @ V) * u   per batch [2048 x 1024 x 2048]
    gemm_m97<2><<<dim3(SEQ / 128, HID / 128, BATCH), 256, 0, stream>>>(
        P, SEQ, (long long)SEQ * SEQ, Vt, SEQ, (long long)HID * SEQ, SEQ, nullptr,
        uv, NHID, (long long)SEQ * NHID, nullptr, 0, hu, nullptr, HID, (long long)SEQ * HID);

    // 8. out = hu @ Wo + bo + x   [16384 x 512 x 1024]
    gemm_m97<3><<<dim3(TOK / 128, DIMC / 128, 1), 256, 0, stream>>>(
        hu, HID, 0, WoT, HID, 0, HID, bo,
        nullptr, 0, 0, x, DIMC, nullptr, out, DIMC, 0);
}

// Round 6
// 283.719 us; speedup vs baseline: 1.1558x; 1.1558x over previous
//
#include <hip/hip_runtime.h>
#include <hip/hip_bf16.h>

typedef short short8 __attribute__((ext_vector_type(8)));
typedef float floatx4 __attribute__((ext_vector_type(4)));

constexpr int BATCH = 8, SEQ = 2048, DIMC = 512, HID = 1024, QKD = 128, NHID = 2176;
constexpr int TOK = BATCH * SEQ;

// workspace layout (bytes)
constexpr size_t OFF_XN  = 0;
constexpr size_t OFF_WHT = OFF_XN  + (size_t)TOK * DIMC * 2;
constexpr size_t OFF_WOT = OFF_WHT + (size_t)NHID * DIMC * 2;
constexpr size_t OFF_UV  = OFF_WOT + (size_t)DIMC * HID * 2;
constexpr size_t OFF_Q   = OFF_UV  + (size_t)TOK * NHID * 2;
constexpr size_t OFF_K   = OFF_Q   + (size_t)TOK * QKD * 2;
constexpr size_t OFF_VT  = OFF_K   + (size_t)TOK * QKD * 2;
constexpr size_t OFF_HU  = OFF_VT  + (size_t)BATCH * HID * SEQ * 2;

__device__ inline void gload_lds16(const __hip_bfloat16* g, __hip_bfloat16* l) {
    __builtin_amdgcn_global_load_lds(
        (const __attribute__((address_space(1))) void*)g,
        (__attribute__((address_space(3))) void*)l, 16, 0, 0);
}

// ---------------- LayerNorm ----------------
__global__ __launch_bounds__(256) void ln_kernel(const float* __restrict__ x,
                                                 const float* __restrict__ w,
                                                 const float* __restrict__ b,
                                                 __hip_bfloat16* __restrict__ xn) {
    int t = blockIdx.x;
    const float* xr = x + (size_t)t * DIMC;
    float2 v = ((const float2*)xr)[threadIdx.x];
    float s = v.x + v.y;
    float ss = v.x * v.x + v.y * v.y;
    for (int o = 32; o; o >>= 1) { s += __shfl_down(s, o); ss += __shfl_down(ss, o); }
    __shared__ float red[8];
    int wid = threadIdx.x >> 6, lane = threadIdx.x & 63;
    if (lane == 0) { red[wid] = s; red[4 + wid] = ss; }
    __syncthreads();
    if (threadIdx.x == 0) {
        float a = red[0] + red[1] + red[2] + red[3];
        float q = red[4] + red[5] + red[6] + red[7];
        float mu = a * (1.0f / DIMC);
        red[0] = mu;
        red[4] = q * (1.0f / DIMC) - mu * mu;
    }
    __syncthreads();
    float mu = red[0];
    float inv = rsqrtf(red[4] + 1e-5f);
    int c = threadIdx.x * 2;
    float y0 = (v.x - mu) * inv * w[c] + b[c];
    float y1 = (v.y - mu) * inv * w[c + 1] + b[c + 1];
    __hip_bfloat16* o = xn + (size_t)t * DIMC + c;
    o[0] = __float2bfloat16(y0);
    o[1] = __float2bfloat16(y1);
}

// ------------- weight convert+transpose -------------
__global__ __launch_bounds__(256) void cvt_kernel(const float* __restrict__ Wh,
                                                  const float* __restrict__ Wo,
                                                  __hip_bfloat16* __restrict__ WhT,
                                                  __hip_bfloat16* __restrict__ WoT) {
    int i = blockIdx.x * 256 + threadIdx.x;
    const int total1 = NHID * DIMC;
    const int total2 = DIMC * HID;
    if (i < total1) {
        int n = i / DIMC, k = i % DIMC;
        WhT[i] = __float2bfloat16(Wh[(size_t)k * NHID + n]);
    } else if (i < total1 + total2) {
        int j = i - total1;
        int d = j / HID, h = j % HID;
        WoT[j] = __float2bfloat16(Wo[(size_t)h * DIMC + d]);
    }
}

// ------------- q/k rotary + key-mask-zero -------------
__global__ __launch_bounds__(256) void qkrot_kernel(const __hip_bfloat16* __restrict__ uv,
                                                    const float* __restrict__ sn,
                                                    const float* __restrict__ cs,
                                                    const int* __restrict__ mask,
                                                    const float* __restrict__ gamma,
                                                    const float* __restrict__ beta,
                                                    __hip_bfloat16* __restrict__ q,
                                                    __hip_bfloat16* __restrict__ k) {
    int t = blockIdx.x * 4 + (threadIdx.x >> 6);
    int j = threadIdx.x & 63;
    const __hip_bfloat16* base = uv + (size_t)t * NHID + 2 * HID;
    float b0 = __bfloat162float(base[2 * j]);
    float b1 = __bfloat162float(base[2 * j + 1]);
    float q0 = b0 * gamma[2 * j] + beta[2 * j];
    float q1 = b1 * gamma[2 * j + 1] + beta[2 * j + 1];
    float k0 = b0 * gamma[QKD + 2 * j] + beta[QKD + 2 * j];
    float k1 = b1 * gamma[QKD + 2 * j + 1] + beta[QKD + 2 * j + 1];
    float s = sn[(size_t)t * 64 + j];
    float c = cs[(size_t)t * 64 + j];
    int bb = t >> 11, nn = t & (SEQ - 1);
    float km = (mask[(size_t)bb * SEQ + nn] != 0) ? 0.f : 1.f;
    q[(size_t)t * QKD + j]       = __float2bfloat16(q0 * c - q1 * s);
    q[(size_t)t * QKD + 64 + j]  = __float2bfloat16(q1 * c + q0 * s);
    k[(size_t)t * QKD + j]       = __float2bfloat16((k0 * c - k1 * s) * km);
    k[(size_t)t * QKD + 64 + j]  = __float2bfloat16((k1 * c + k0 * s) * km);
}

// ------------- V transpose: uv[:,1024:2048] -> Vt[b][h][n] -------------
__global__ __launch_bounds__(256) void vt_kernel(const __hip_bfloat16* __restrict__ uv,
                                                 __hip_bfloat16* __restrict__ Vt) {
    __shared__ __hip_bfloat16 tile[64][65];
    int n0 = blockIdx.x * 64, h0 = blockIdx.y * 64, b = blockIdx.z;
    #pragma unroll
    for (int i = 0; i < 16; i++) {
        int idx = i * 256 + threadIdx.x;
        int r = idx >> 6, c = idx & 63;
        tile[r][c] = uv[((size_t)(b * SEQ + n0 + r)) * NHID + HID + h0 + c];
    }
    __syncthreads();
    #pragma unroll
    for (int i = 0; i < 16; i++) {
        int idx = i * 256 + threadIdx.x;
        int r = idx >> 6, c = idx & 63;
        Vt[((size_t)b * HID + h0 + r) * SEQ + n0 + c] = tile[c][r];
    }
}

// ============ fused attention: P never leaves the CU ============
// Block = (batch b, 64-row Q-tile). 8 waves: wave w computes 2 S-frags
// (mw=w>>1, nw0=(w&1)*2 .. +1) shared via LDS P-tile; PV: wave owns h-cols
// [w*128, w*128+128), acc[4][8] in regs. One barrier per K-tile:
//  A) stage K[nxt] (kt+1)   B) prefetch V(ki=0)   C) QK^T reads K[cur]
//  D) P-write -> Pl[cur]    E) __syncthreads      F) PV reads Pl[cur]
// Hazards: A vs C(kt-1) on same buf: separated by E(kt-1) (A is after it,
// C before it, barrier orders cross-wave). D(kt+2) vs F(kt) on Pl[cur]:
// separated by E(kt+1). All others touch disjoint buffers.
__global__ __launch_bounds__(512, 1) void attn_kernel(
    const __hip_bfloat16* __restrict__ qg_, const __hip_bfloat16* __restrict__ kg_,
    const __hip_bfloat16* __restrict__ Vt, const __hip_bfloat16* __restrict__ uv,
    __hip_bfloat16* __restrict__ hu) {
    __shared__ __hip_bfloat16 Kl[2][64 * 128];   // 32 KB, read-swizzle ^(row&15)
    __shared__ __hip_bfloat16 Pl[2][64 * 64];    // 16 KB, read-swizzle ^(row&7); holds Q at start

    int bid = blockIdx.x;
    int swz = (bid & 7) * 32 + (bid >> 3);       // batch ~ XCD
    int b = swz >> 5, qt = swz & 31;
    int tid = threadIdx.x, l = tid & 63, w = tid >> 6;
    int mw = w >> 1, nw0 = (w & 1) * 2;
    int h0 = w * 128;
    int r16 = l & 15, l4 = l >> 4;

    const __hip_bfloat16* qg = qg_ + ((size_t)b * SEQ + qt * 64) * QKD;
    const __hip_bfloat16* kg = kg_ + (size_t)b * SEQ * QKD;
    const __hip_bfloat16* vg = Vt + (size_t)b * HID * SEQ;

    __hip_bfloat16* Ql = &Pl[0][0];              // 8192 elems = both P buffers

    // prologue: stage Q [64][128] and K-tile 0 (swizzled source chunk)
    #pragma unroll
    for (int j = 0; j < 2; j++) {
        int r0 = w * 8 + j * 4;
        int row = r0 + l4;
        int sc = ((l & 15) ^ (row & 15)) * 8;
        gload_lds16(&qg[(size_t)row * QKD + sc], &Ql[r0 * 128]);
        gload_lds16(&kg[(size_t)row * QKD + sc], &Kl[0][r0 * 128]);
    }
    __syncthreads();
    short8 qf[4];
    #pragma unroll
    for (int ki = 0; ki < 4; ki++) {
        int row = mw * 16 + r16;
        int c = ki * 4 + l4;
        qf[ki] = *(const short8*)&Ql[row * 128 + ((c ^ (row & 15)) << 3)];
    }
    __syncthreads();   // before Pl (=Q region) is overwritten by P-writes

    floatx4 acc[4][8] = {};   // [m][nh]

    for (int kt = 0; kt < 32; kt++) {
        int cur = kt & 1, nxt = cur ^ 1;
        int ktn = (kt + 1 < 32) ? kt + 1 : 31;
        // A) stage next K-tile
        #pragma unroll
        for (int j = 0; j < 2; j++) {
            int r0 = w * 8 + j * 4;
            int row = r0 + l4;
            int sc = ((l & 15) ^ (row & 15)) * 8;
            gload_lds16(&kg[((size_t)ktn * 64 + row) * QKD + sc], &Kl[nxt][r0 * 128]);
        }
        // B) prefetch V frags for ki=0 (landed by the E-drain)
        short8 vf0[8];
        #pragma unroll
        for (int nh = 0; nh < 8; nh++)
            vf0[nh] = *(const short8*)&vg[(size_t)(h0 + nh * 16 + r16) * SEQ + kt * 64 + l4 * 8];
        // C) QK^T -> 2 S-frags
        floatx4 s0 = {0.f, 0.f, 0.f, 0.f}, s1 = {0.f, 0.f, 0.f, 0.f};
        #pragma unroll
        for (int ki = 0; ki < 4; ki++) {
            int rowa = nw0 * 16 + r16;
            int rowb = rowa + 16;
            int c = ki * 4 + l4;
            short8 kf0 = *(const short8*)&Kl[cur][rowa * 128 + ((c ^ (rowa & 15)) << 3)];
            short8 kf1 = *(const short8*)&Kl[cur][rowb * 128 + ((c ^ (rowb & 15)) << 3)];
            s0 = __builtin_amdgcn_mfma_f32_16x16x32_bf16(qf[ki], kf0, s0, 0, 0, 0);
            s1 = __builtin_amdgcn_mfma_f32_16x16x32_bf16(qf[ki], kf1, s1, 0, 0, 0);
        }
        // D) P = relu(s)^2/32768 -> bf16 -> Pl[cur] (chunk-swizzled)
        #pragma unroll
        for (int f = 0; f < 2; f++) {
            floatx4 sv = f ? s1 : s0;
            #pragma unroll
            for (int i = 0; i < 4; i++) {
                float v = sv[i];
                v = v > 0.f ? v * v * (1.f / 32768.f) : 0.f;
                int row = mw * 16 + l4 * 4 + i;
                int col = (nw0 + f) * 16 + r16;
                int ch = col >> 3;
                Pl[cur][row * 64 + (((ch ^ (row & 7)) << 3) | (col & 7))] = __float2bfloat16(v);
            }
        }
        // E)
        __syncthreads();
        // F) PV
        #pragma unroll
        for (int ki = 0; ki < 2; ki++) {
            short8 pa[4];
            #pragma unroll
            for (int m = 0; m < 4; m++) {
                int row = m * 16 + r16;
                int c = ki * 4 + l4;
                pa[m] = *(const short8*)&Pl[cur][row * 64 + ((c ^ (row & 7)) << 3)];
            }
            short8 vf[8];
            #pragma unroll
            for (int nh = 0; nh < 8; nh++) {
                if (ki == 0) vf[nh] = vf0[nh];
                else vf[nh] = *(const short8*)&vg[(size_t)(h0 + nh * 16 + r16) * SEQ + kt * 64 + 32 + l4 * 8];
            }
            #pragma unroll
            for (int m = 0; m < 4; m++)
                #pragma unroll
                for (int nh = 0; nh < 8; nh++)
                    acc[m][nh] = __builtin_amdgcn_mfma_f32_16x16x32_bf16(pa[m], vf[nh], acc[m][nh], 0, 0, 0);
        }
    }

    // epilogue: hu = acc * u
    #pragma unroll
    for (int m = 0; m < 4; m++) {
        #pragma unroll
        for (int nh = 0; nh < 8; nh++) {
            #pragma unroll
            for (int i = 0; i < 4; i++) {
                int row = qt * 64 + m * 16 + l4 * 4 + i;
                int col = h0 + nh * 16 + r16;
                float u = __bfloat162float(uv[((size_t)b * SEQ + row) * NHID + col]);
                hu[((size_t)b * SEQ + row) * HID + col] = __float2bfloat16(acc[m][nh][i] * u);
            }
        }
    }
}

// ============ R3-proven interleaved GEMM BM=256,BN=128,BK=64 ============
// Triple-buffered LDS (144KB), 2-tile-ahead prefetch, counted vmcnt(6).
// EPI 0: silu(acc+bias)->bf16 | EPI 3: acc+bias+Xres->f32
template <int EPI>
__global__ __launch_bounds__(512, 1) void gemm8p(
    const __hip_bfloat16* __restrict__ A, int lda,
    const __hip_bfloat16* __restrict__ Bt, int ldb,
    int K,
    const float* __restrict__ bias,
    const float* __restrict__ Xres, int ldx,
    __hip_bfloat16* __restrict__ Cb, float* __restrict__ Cf, int ldc) {
    __shared__ __hip_bfloat16 As[3][256 * 64];
    __shared__ __hip_bfloat16 Bs[3][128 * 64];

    int m0 = blockIdx.x * 256, n0 = blockIdx.y * 128;
    int tid = threadIdx.x, l = tid & 63, w = tid >> 6;
    int wm = w >> 1, wn = w & 1;
    int nt = K >> 6;

    floatx4 acc[4][4] = {};

    int srow = l >> 3;
    int sch = ((l & 7) ^ (l >> 3)) * 8;
    int r16 = l & 15, khi = l >> 4;

    #define FRAG8(buf, row, kc) (*(const short8*)&(buf)[(row) * 64 + (((kc) ^ ((row) & 7)) << 3)])
    #define STAGE_A8(j, kt, bsel) { int cidx = (j) * 8 + w; \
        gload_lds16(&A[(size_t)(m0 + cidx * 8 + srow) * lda + (kt) + sch], &As[bsel][cidx * 512]); }
    #define STAGE_B8(j, kt, bsel) { int cidx = (j) * 8 + w; \
        gload_lds16(&Bt[(size_t)(n0 + cidx * 8 + srow) * ldb + (kt) + sch], &Bs[bsel][cidx * 512]); }

    {
        STAGE_A8(0, 0, 0) STAGE_A8(1, 0, 0) STAGE_A8(2, 0, 0) STAGE_A8(3, 0, 0)
        STAGE_B8(0, 0, 0) STAGE_B8(1, 0, 0)
        int k1 = (nt > 1) ? 64 : 0;
        STAGE_A8(0, k1, 1) STAGE_A8(1, k1, 1) STAGE_A8(2, k1, 1) STAGE_A8(3, k1, 1)
        STAGE_B8(0, k1, 1) STAGE_B8(1, k1, 1)
        asm volatile("s_waitcnt vmcnt(6)" ::: "memory");
        __builtin_amdgcn_s_barrier();
    }

    for (int t = 0; t < nt; ++t) {
        const __hip_bfloat16* a_lds = As[t % 3];
        const __hip_bfloat16* b_lds = Bs[t % 3];
        int bn = (t + 2) % 3;
        int tt = (t + 2) < nt ? (t + 2) : (nt - 1);
        int ktn = tt << 6;

        {
            short8 a[4], b[4];
            #pragma unroll
            for (int m = 0; m < 4; m++) a[m] = FRAG8(a_lds, wm * 64 + m * 16 + r16, khi);
            #pragma unroll
            for (int n = 0; n < 4; n++) b[n] = FRAG8(b_lds, wn * 64 + n * 16 + r16, khi);
            STAGE_A8(0, ktn, bn) STAGE_A8(1, ktn, bn) STAGE_B8(0, ktn, bn)
            __builtin_amdgcn_s_barrier();
            asm volatile("s_waitcnt lgkmcnt(0)" ::: "memory");
            __builtin_amdgcn_sched_barrier(0);
            __builtin_amdgcn_s_setprio(1);
            #pragma unroll
            for (int m = 0; m < 4; m++)
                #pragma unroll
                for (int n = 0; n < 4; n++)
                    acc[m][n] = __builtin_amdgcn_mfma_f32_16x16x32_bf16(a[m], b[n], acc[m][n], 0, 0, 0);
            __builtin_amdgcn_s_setprio(0);
            __builtin_amdgcn_s_barrier();
        }
        {
            short8 a[4], b[4];
            #pragma unroll
            for (int m = 0; m < 4; m++) a[m] = FRAG8(a_lds, wm * 64 + m * 16 + r16, 4 + khi);
            #pragma unroll
            for (int n = 0; n < 4; n++) b[n] = FRAG8(b_lds, wn * 64 + n * 16 + r16, 4 + khi);
            STAGE_A8(2, ktn, bn) STAGE_A8(3, ktn, bn) STAGE_B8(1, ktn, bn)
            __builtin_amdgcn_s_barrier();
            asm volatile("s_waitcnt lgkmcnt(0)" ::: "memory");
            __builtin_amdgcn_sched_barrier(0);
            __builtin_amdgcn_s_setprio(1);
            #pragma unroll
            for (int m = 0; m < 4; m++)
                #pragma unroll
                for (int n = 0; n < 4; n++)
                    acc[m][n] = __builtin_amdgcn_mfma_f32_16x16x32_bf16(a[m], b[n], acc[m][n], 0, 0, 0);
            __builtin_amdgcn_s_setprio(0);
            asm volatile("s_waitcnt vmcnt(6)" ::: "memory");
            __builtin_amdgcn_s_barrier();
        }
    }

    #pragma unroll
    for (int m = 0; m < 4; m++)
        #pragma unroll
        for (int n = 0; n < 4; n++)
            #pragma unroll
            for (int i = 0; i < 4; i++) {
                int row = m0 + wm * 64 + m * 16 + khi * 4 + i;
                int col = n0 + wn * 64 + n * 16 + r16;
                float v = acc[m][n][i];
                if (EPI == 0) {
                    v += bias[col];
                    v = v / (1.0f + __expf(-v));
                    Cb[(size_t)row * ldc + col] = __float2bfloat16(v);
                } else {
                    v += bias[col] + Xres[(size_t)row * ldx + col];
                    Cf[(size_t)row * ldc + col] = v;
                }
            }
    #undef FRAG8
    #undef STAGE_A8
    #undef STAGE_B8
}

extern "C" void kernel_launch(void* const* d_in, const int* in_sizes, int n_in,
                              void* d_out, int out_size, void* d_ws, size_t ws_size,
                              hipStream_t stream) {
    const float* x     = (const float*)d_in[0];
    const float* msin  = (const float*)d_in[1];
    const float* mcos  = (const float*)d_in[2];
    const int*   mask  = (const int*)d_in[3];
    const float* lnw   = (const float*)d_in[4];
    const float* lnb   = (const float*)d_in[5];
    const float* Wh    = (const float*)d_in[6];
    const float* bh    = (const float*)d_in[7];
    const float* gamma = (const float*)d_in[8];
    const float* beta  = (const float*)d_in[9];
    const float* Wo    = (const float*)d_in[10];
    const float* bo    = (const float*)d_in[11];
    float* out = (float*)d_out;
    char* ws = (char*)d_ws;

    __hip_bfloat16* xn  = (__hip_bfloat16*)(ws + OFF_XN);
    __hip_bfloat16* WhT = (__hip_bfloat16*)(ws + OFF_WHT);
    __hip_bfloat16* WoT = (__hip_bfloat16*)(ws + OFF_WOT);
    __hip_bfloat16* uv  = (__hip_bfloat16*)(ws + OFF_UV);
    __hip_bfloat16* q   = (__hip_bfloat16*)(ws + OFF_Q);
    __hip_bfloat16* k   = (__hip_bfloat16*)(ws + OFF_K);
    __hip_bfloat16* Vt  = (__hip_bfloat16*)(ws + OFF_VT);
    __hip_bfloat16* hu  = (__hip_bfloat16*)(ws + OFF_HU);

    // 1. LayerNorm -> xn (bf16)
    ln_kernel<<<TOK, 256, 0, stream>>>(x, lnw, lnb, xn);

    // 2. weight transpose/convert
    cvt_kernel<<<(NHID * DIMC + DIMC * HID + 255) / 256, 256, 0, stream>>>(Wh, Wo, WhT, WoT);

    // 3. GEMM1: uv = silu(xn @ Wh + bh)   [16384 x 2176 x 512]
    gemm8p<0><<<dim3(TOK / 256, NHID / 128), 512, 0, stream>>>(
        xn, DIMC, WhT, DIMC, DIMC, bh, nullptr, 0, uv, nullptr, NHID);

    // 4. q/k rotary, masked keys zeroed
    qkrot_kernel<<<TOK / 4, 256, 0, stream>>>(uv, msin, mcos, mask, gamma, beta, q, k);

    // 5. V transpose per batch
    vt_kernel<<<dim3(SEQ / 64, HID / 64, BATCH), 256, 0, stream>>>(uv, Vt);

    // 6+7. fused attention: hu = (relu(qk^T)^2/32768 @ V) * u
    attn_kernel<<<256, 512, 0, stream>>>(q, k, Vt, uv, hu);

    // 8. out = hu @ Wo + bo + x   [16384 x 512 x 1024]
    gemm8p<3><<<dim3(TOK / 256, DIMC / 128), 512, 0, stream>>>(
        hu, HID, WoT, HID, HID, bo, x, DIMC, nullptr, out, DIMC);
}

// Round 7
// 255.267 us; speedup vs baseline: 1.2847x; 1.1115x over previous
//
#include <hip/hip_runtime.h>
#include <hip/hip_bf16.h>

typedef short short8 __attribute__((ext_vector_type(8)));
typedef float floatx4 __attribute__((ext_vector_type(4)));

constexpr int BATCH = 8, SEQ = 2048, DIMC = 512, HID = 1024, QKD = 128, NHID = 2176;
constexpr int NHIDP = 2304;   // padded N for 256-wide tiles
constexpr int TOK = BATCH * SEQ;

// workspace layout (bytes)
constexpr size_t OFF_XN  = 0;
constexpr size_t OFF_WHT = OFF_XN  + (size_t)TOK * DIMC * 2;
constexpr size_t OFF_WOT = OFF_WHT + (size_t)NHIDP * DIMC * 2;
constexpr size_t OFF_UV  = OFF_WOT + (size_t)DIMC * HID * 2;
constexpr size_t OFF_Q   = OFF_UV  + (size_t)TOK * NHID * 2;
constexpr size_t OFF_K   = OFF_Q   + (size_t)TOK * QKD * 2;
constexpr size_t OFF_VT  = OFF_K   + (size_t)TOK * QKD * 2;
constexpr size_t OFF_P   = OFF_VT  + (size_t)BATCH * HID * SEQ * 2;
constexpr size_t OFF_HU  = OFF_P   + (size_t)BATCH * SEQ * SEQ * 2;

__device__ inline void gload_lds16(const __hip_bfloat16* g, __hip_bfloat16* l) {
    __builtin_amdgcn_global_load_lds(
        (const __attribute__((address_space(1))) void*)g,
        (__attribute__((address_space(3))) void*)l, 16, 0, 0);
}

// ---------------- LayerNorm ----------------
__global__ __launch_bounds__(256) void ln_kernel(const float* __restrict__ x,
                                                 const float* __restrict__ w,
                                                 const float* __restrict__ b,
                                                 __hip_bfloat16* __restrict__ xn) {
    int t = blockIdx.x;
    const float* xr = x + (size_t)t * DIMC;
    float2 v = ((const float2*)xr)[threadIdx.x];
    float s = v.x + v.y;
    float ss = v.x * v.x + v.y * v.y;
    for (int o = 32; o; o >>= 1) { s += __shfl_down(s, o); ss += __shfl_down(ss, o); }
    __shared__ float red[8];
    int wid = threadIdx.x >> 6, lane = threadIdx.x & 63;
    if (lane == 0) { red[wid] = s; red[4 + wid] = ss; }
    __syncthreads();
    if (threadIdx.x == 0) {
        float a = red[0] + red[1] + red[2] + red[3];
        float q = red[4] + red[5] + red[6] + red[7];
        float mu = a * (1.0f / DIMC);
        red[0] = mu;
        red[4] = q * (1.0f / DIMC) - mu * mu;
    }
    __syncthreads();
    float mu = red[0];
    float inv = rsqrtf(red[4] + 1e-5f);
    int c = threadIdx.x * 2;
    float y0 = (v.x - mu) * inv * w[c] + b[c];
    float y1 = (v.y - mu) * inv * w[c + 1] + b[c + 1];
    __hip_bfloat16* o = xn + (size_t)t * DIMC + c;
    o[0] = __float2bfloat16(y0);
    o[1] = __float2bfloat16(y1);
}

// ------------- weight convert+transpose (WhT padded to NHIDP rows) -------------
__global__ __launch_bounds__(256) void cvt_kernel(const float* __restrict__ Wh,
                                                  const float* __restrict__ Wo,
                                                  __hip_bfloat16* __restrict__ WhT,
                                                  __hip_bfloat16* __restrict__ WoT) {
    int i = blockIdx.x * 256 + threadIdx.x;
    const int total1 = NHIDP * DIMC;
    const int total2 = DIMC * HID;
    if (i < total1) {
        int n = i / DIMC, k = i % DIMC;
        WhT[i] = (n < NHID) ? __float2bfloat16(Wh[(size_t)k * NHID + n]) : __float2bfloat16(0.0f);
    } else if (i < total1 + total2) {
        int j = i - total1;
        int d = j / HID, h = j % HID;
        WoT[j] = __float2bfloat16(Wo[(size_t)h * DIMC + d]);
    }
}

// ------------- q/k rotary + key-mask-zero -------------
__global__ __launch_bounds__(256) void qkrot_kernel(const __hip_bfloat16* __restrict__ uv,
                                                    const float* __restrict__ sn,
                                                    const float* __restrict__ cs,
                                                    const int* __restrict__ mask,
                                                    const float* __restrict__ gamma,
                                                    const float* __restrict__ beta,
                                                    __hip_bfloat16* __restrict__ q,
                                                    __hip_bfloat16* __restrict__ k) {
    int t = blockIdx.x * 4 + (threadIdx.x >> 6);
    int j = threadIdx.x & 63;
    const __hip_bfloat16* base = uv + (size_t)t * NHID + 2 * HID;
    float b0 = __bfloat162float(base[2 * j]);
    float b1 = __bfloat162float(base[2 * j + 1]);
    float q0 = b0 * gamma[2 * j] + beta[2 * j];
    float q1 = b1 * gamma[2 * j + 1] + beta[2 * j + 1];
    float k0 = b0 * gamma[QKD + 2 * j] + beta[QKD + 2 * j];
    float k1 = b1 * gamma[QKD + 2 * j + 1] + beta[QKD + 2 * j + 1];
    float s = sn[(size_t)t * 64 + j];
    float c = cs[(size_t)t * 64 + j];
    int bb = t >> 11, nn = t & (SEQ - 1);
    float km = (mask[(size_t)bb * SEQ + nn] != 0) ? 0.f : 1.f;
    q[(size_t)t * QKD + j]       = __float2bfloat16(q0 * c - q1 * s);
    q[(size_t)t * QKD + 64 + j]  = __float2bfloat16(q1 * c + q0 * s);
    k[(size_t)t * QKD + j]       = __float2bfloat16((k0 * c - k1 * s) * km);
    k[(size_t)t * QKD + 64 + j]  = __float2bfloat16((k1 * c + k0 * s) * km);
}

// ------------- V transpose -------------
__global__ __launch_bounds__(256) void vt_kernel(const __hip_bfloat16* __restrict__ uv,
                                                 __hip_bfloat16* __restrict__ Vt) {
    __shared__ __hip_bfloat16 tile[64][65];
    int n0 = blockIdx.x * 64, h0 = blockIdx.y * 64, b = blockIdx.z;
    #pragma unroll
    for (int i = 0; i < 16; i++) {
        int idx = i * 256 + threadIdx.x;
        int r = idx >> 6, c = idx & 63;
        tile[r][c] = uv[((size_t)(b * SEQ + n0 + r)) * NHID + HID + h0 + c];
    }
    __syncthreads();
    #pragma unroll
    for (int i = 0; i < 16; i++) {
        int idx = i * 256 + threadIdx.x;
        int r = idx >> 6, c = idx & 63;
        Vt[((size_t)b * HID + h0 + r) * SEQ + n0 + c] = tile[c][r];
    }
}

// ============ padded-LDS 128x128 GEMM (QK^T) ============
template <int EPI>
__global__ __launch_bounds__(256) void gemm_small(
    const __hip_bfloat16* __restrict__ A, int lda, long long sA,
    const __hip_bfloat16* __restrict__ Bt, int ldb, long long sB,
    int K,
    __hip_bfloat16* __restrict__ Cb, int ldc, long long sC) {
    __shared__ __hip_bfloat16 As[128][72];
    __shared__ __hip_bfloat16 Bs[128][72];

    if (sA) A += (size_t)blockIdx.z * sA;
    if (sB) Bt += (size_t)blockIdx.z * sB;
    if (sC) Cb += (size_t)blockIdx.z * sC;

    int m0 = blockIdx.x * 128, n0 = blockIdx.y * 128;
    int tid = threadIdx.x, lane = tid & 63, wid = tid >> 6;
    int wr = (wid >> 1) * 64, wc = (wid & 1) * 64;

    floatx4 acc[4][4] = {};
    int row_a = tid >> 3;
    int cv = tid & 7;

    for (int kt = 0; kt < K; kt += 64) {
        #pragma unroll
        for (int i = 0; i < 4; i++) {
            int r = row_a + i * 32;
            *(uint4*)&As[r][cv * 8] = *(const uint4*)&A[((size_t)(m0 + r)) * lda + kt + cv * 8];
            *(uint4*)&Bs[r][cv * 8] = *(const uint4*)&Bt[((size_t)(n0 + r)) * ldb + kt + cv * 8];
        }
        __syncthreads();
        #pragma unroll
        for (int ko = 0; ko < 2; ko++) {
            short8 a[4], b[4];
            int rr = lane & 15;
            int kb = ko * 32 + (lane >> 4) * 8;
            #pragma unroll
            for (int m = 0; m < 4; m++) a[m] = *(const short8*)&As[wr + m * 16 + rr][kb];
            #pragma unroll
            for (int n = 0; n < 4; n++) b[n] = *(const short8*)&Bs[wc + n * 16 + rr][kb];
            #pragma unroll
            for (int m = 0; m < 4; m++)
                #pragma unroll
                for (int n = 0; n < 4; n++)
                    acc[m][n] = __builtin_amdgcn_mfma_f32_16x16x32_bf16(a[m], b[n], acc[m][n], 0, 0, 0);
        }
        __syncthreads();
    }

    int r4 = (lane >> 4) * 4, cc = lane & 15;
    #pragma unroll
    for (int m = 0; m < 4; m++)
        #pragma unroll
        for (int n = 0; n < 4; n++)
            #pragma unroll
            for (int i = 0; i < 4; i++) {
                int row = m0 + wr + m * 16 + r4 + i;
                int col = n0 + wc + n * 16 + cc;
                float v = acc[m][n][i];
                if (EPI == 1) v = v > 0.0f ? v * v * (1.0f / 32768.0f) : 0.0f;
                Cb[(size_t)row * ldc + col] = __float2bfloat16(v);
            }
}

// ============ R3 interleaved GEMM BM=256,BN=128 (final, EPI3) + XCD stripe ============
__global__ __launch_bounds__(512, 1) void gemm8p_final(
    const __hip_bfloat16* __restrict__ A, int lda,
    const __hip_bfloat16* __restrict__ Bt, int ldb,
    int K,
    const float* __restrict__ bias,
    const float* __restrict__ Xres, int ldx,
    float* __restrict__ Cf, int ldc) {
    __shared__ __hip_bfloat16 As[3][256 * 64];
    __shared__ __hip_bfloat16 Bs[3][128 * 64];

    // XCD stripe raster: xcd owns 8 contiguous m-tiles, n iterates fastest
    int lin = blockIdx.x + gridDim.x * blockIdx.y;
    int xcd = lin & 7, j = lin >> 3;
    int gy = gridDim.y;
    int mt = xcd * (gridDim.x >> 3) + j / gy;
    int nt = j % gy;
    int m0 = mt * 256, n0 = nt * 128;

    int tid = threadIdx.x, l = tid & 63, w = tid >> 6;
    int wm = w >> 1, wn = w & 1;
    int ntk = K >> 6;

    floatx4 acc[4][4] = {};

    int srow = l >> 3;
    int sch = ((l & 7) ^ (l >> 3)) * 8;
    int r16 = l & 15, khi = l >> 4;

    #define FRAG8(buf, row, kc) (*(const short8*)&(buf)[(row) * 64 + (((kc) ^ ((row) & 7)) << 3)])
    #define STAGE_A8(jj, kt, bsel) { int cidx = (jj) * 8 + w; \
        gload_lds16(&A[(size_t)(m0 + cidx * 8 + srow) * lda + (kt) + sch], &As[bsel][cidx * 512]); }
    #define STAGE_B8(jj, kt, bsel) { int cidx = (jj) * 8 + w; \
        gload_lds16(&Bt[(size_t)(n0 + cidx * 8 + srow) * ldb + (kt) + sch], &Bs[bsel][cidx * 512]); }

    {
        STAGE_A8(0, 0, 0) STAGE_A8(1, 0, 0) STAGE_A8(2, 0, 0) STAGE_A8(3, 0, 0)
        STAGE_B8(0, 0, 0) STAGE_B8(1, 0, 0)
        int k1 = (ntk > 1) ? 64 : 0;
        STAGE_A8(0, k1, 1) STAGE_A8(1, k1, 1) STAGE_A8(2, k1, 1) STAGE_A8(3, k1, 1)
        STAGE_B8(0, k1, 1) STAGE_B8(1, k1, 1)
        asm volatile("s_waitcnt vmcnt(6)" ::: "memory");
        __builtin_amdgcn_s_barrier();
    }

    for (int t = 0; t < ntk; ++t) {
        const __hip_bfloat16* a_lds = As[t % 3];
        const __hip_bfloat16* b_lds = Bs[t % 3];
        int bn = (t + 2) % 3;
        int tt = (t + 2) < ntk ? (t + 2) : (ntk - 1);
        int ktn = tt << 6;

        {
            short8 a[4], b[4];
            #pragma unroll
            for (int m = 0; m < 4; m++) a[m] = FRAG8(a_lds, wm * 64 + m * 16 + r16, khi);
            #pragma unroll
            for (int n = 0; n < 4; n++) b[n] = FRAG8(b_lds, wn * 64 + n * 16 + r16, khi);
            STAGE_A8(0, ktn, bn) STAGE_A8(1, ktn, bn) STAGE_B8(0, ktn, bn)
            __builtin_amdgcn_s_barrier();
            asm volatile("s_waitcnt lgkmcnt(0)" ::: "memory");
            __builtin_amdgcn_sched_barrier(0);
            __builtin_amdgcn_s_setprio(1);
            #pragma unroll
            for (int m = 0; m < 4; m++)
                #pragma unroll
                for (int n = 0; n < 4; n++)
                    acc[m][n] = __builtin_amdgcn_mfma_f32_16x16x32_bf16(a[m], b[n], acc[m][n], 0, 0, 0);
            __builtin_amdgcn_s_setprio(0);
            __builtin_amdgcn_s_barrier();
        }
        {
            short8 a[4], b[4];
            #pragma unroll
            for (int m = 0; m < 4; m++) a[m] = FRAG8(a_lds, wm * 64 + m * 16 + r16, 4 + khi);
            #pragma unroll
            for (int n = 0; n < 4; n++) b[n] = FRAG8(b_lds, wn * 64 + n * 16 + r16, 4 + khi);
            STAGE_A8(2, ktn, bn) STAGE_A8(3, ktn, bn) STAGE_B8(1, ktn, bn)
            __builtin_amdgcn_s_barrier();
            asm volatile("s_waitcnt lgkmcnt(0)" ::: "memory");
            __builtin_amdgcn_sched_barrier(0);
            __builtin_amdgcn_s_setprio(1);
            #pragma unroll
            for (int m = 0; m < 4; m++)
                #pragma unroll
                for (int n = 0; n < 4; n++)
                    acc[m][n] = __builtin_amdgcn_mfma_f32_16x16x32_bf16(a[m], b[n], acc[m][n], 0, 0, 0);
            __builtin_amdgcn_s_setprio(0);
            asm volatile("s_waitcnt vmcnt(6)" ::: "memory");
            __builtin_amdgcn_s_barrier();
        }
    }

    #pragma unroll
    for (int m = 0; m < 4; m++)
        #pragma unroll
        for (int n = 0; n < 4; n++)
            #pragma unroll
            for (int i = 0; i < 4; i++) {
                int row = m0 + wm * 64 + m * 16 + khi * 4 + i;
                int col = n0 + wn * 64 + n * 16 + r16;
                float v = acc[m][n][i] + bias[col] + Xres[(size_t)row * ldx + col];
                Cf[(size_t)row * ldc + col] = v;
            }
    #undef FRAG8
    #undef STAGE_A8
    #undef STAGE_B8
}

// ============ 256x256 GEMM: BK=32, triple-buffer, wave tile 128x64 ============
// RAS 0: XCD m-stripe, n fastest (needs gridDim.x % 8 == 0)
// RAS 1: flat decode, batch = fid&7 ~ XCD (PV: grid (8,4,8))
template <int EPI, int RAS>
__global__ __launch_bounds__(512, 1) void gemm256(
    const __hip_bfloat16* __restrict__ A, int lda, long long sA,
    const __hip_bfloat16* __restrict__ Bt, int ldb, long long sB,
    int K, int Nact,
    const float* __restrict__ bias,
    const __hip_bfloat16* __restrict__ U, int ldu, long long sU,
    __hip_bfloat16* __restrict__ Cb, int ldc, long long sC) {
    __shared__ __hip_bfloat16 As[3][2][128 * 32];
    __shared__ __hip_bfloat16 Bs[3][2][128 * 32];

    int m0, n0;
    if (RAS == 0) {
        int lin = blockIdx.x + gridDim.x * blockIdx.y;
        int xcd = lin & 7, j = lin >> 3;
        int gy = gridDim.y;
        int mt = xcd * (gridDim.x >> 3) + j / gy;
        int nt = j % gy;
        m0 = mt * 256; n0 = nt * 256;
    } else {
        // PV: grid (8,4,8); fid = x + 8y + 32z; batch = fid&7 -> XCD-resident Vt
        int fid = blockIdx.x + gridDim.x * (blockIdx.y + gridDim.y * blockIdx.z);
        int b = fid & 7;
        int r = fid >> 3;
        m0 = (r >> 2) * 256; n0 = (r & 3) * 256;
        A += (size_t)b * sA;
        Bt += (size_t)b * sB;
        Cb += (size_t)b * sC;
        if (U) U += (size_t)b * sU;
    }

    int tid = threadIdx.x, l = tid & 63, w = tid >> 6;
    int wm = w >> 2, wn = w & 3;
    int bo = (wn & 1) * 64;
    int nt = K >> 5;

    int strow = w * 16 + (l >> 2);
    int stch = ((l & 3) ^ ((l >> 3) & 3)) << 3;
    int r16 = l & 15, kc = l >> 4;

    floatx4 acc[8][4] = {};

    #define FRAG(P, lrow, kk) (*(const short8*)&(P)[(lrow) * 32 + ((((kk) ^ (((lrow) >> 1) & 3))) << 3)])
    #define STAGE_A(buf, h, ts) gload_lds16(&A[(size_t)(m0 + (h) * 128 + strow) * lda + (ts) * 32 + stch], &As[buf][h][w * 512]);
    #define STAGE_B(buf, h, ts) gload_lds16(&Bt[(size_t)(n0 + (h) * 128 + strow) * ldb + (ts) * 32 + stch], &Bs[buf][h][w * 512]);

    STAGE_A(0, 0, 0) STAGE_A(0, 1, 0) STAGE_B(0, 0, 0) STAGE_B(0, 1, 0)
    STAGE_A(1, 0, 1) STAGE_A(1, 1, 1) STAGE_B(1, 0, 1) STAGE_B(1, 1, 1)
    asm volatile("s_waitcnt vmcnt(4)" ::: "memory");
    __builtin_amdgcn_s_barrier();

    for (int t = 0; t < nt; ++t) {
        const __hip_bfloat16* Ah = As[t % 3][wm];
        const __hip_bfloat16* Bh = Bs[t % 3][wn >> 1];
        int bsel = (t + 2) % 3;
        int ts = (t + 2) < nt ? (t + 2) : (nt - 1);

        short8 b[4];
        {
            short8 a[4];
            #pragma unroll
            for (int m = 0; m < 4; m++) a[m] = FRAG(Ah, m * 16 + r16, kc);
            #pragma unroll
            for (int n = 0; n < 4; n++) b[n] = FRAG(Bh, bo + n * 16 + r16, kc);
            STAGE_A(bsel, 0, ts) STAGE_A(bsel, 1, ts)
            __builtin_amdgcn_s_barrier();
            asm volatile("s_waitcnt lgkmcnt(0)" ::: "memory");
            __builtin_amdgcn_sched_barrier(0);
            __builtin_amdgcn_s_setprio(1);
            #pragma unroll
            for (int m = 0; m < 4; m++)
                #pragma unroll
                for (int n = 0; n < 4; n++)
                    acc[m][n] = __builtin_amdgcn_mfma_f32_16x16x32_bf16(a[m], b[n], acc[m][n], 0, 0, 0);
            __builtin_amdgcn_s_setprio(0);
            __builtin_amdgcn_s_barrier();
        }
        {
            short8 a[4];
            #pragma unroll
            for (int m = 0; m < 4; m++) a[m] = FRAG(Ah, (m + 4) * 16 + r16, kc);
            STAGE_B(bsel, 0, ts) STAGE_B(bsel, 1, ts)
            __builtin_amdgcn_s_barrier();
            asm volatile("s_waitcnt lgkmcnt(0)" ::: "memory");
            __builtin_amdgcn_sched_barrier(0);
            __builtin_amdgcn_s_setprio(1);
            #pragma unroll
            for (int m = 0; m < 4; m++)
                #pragma unroll
                for (int n = 0; n < 4; n++)
                    acc[m + 4][n] = __builtin_amdgcn_mfma_f32_16x16x32_bf16(a[m], b[n], acc[m + 4][n], 0, 0, 0);
            __builtin_amdgcn_s_setprio(0);
            asm volatile("s_waitcnt vmcnt(4)" ::: "memory");
            __builtin_amdgcn_s_barrier();
        }
    }

    #pragma unroll
    for (int m = 0; m < 8; m++) {
        #pragma unroll
        for (int n = 0; n < 4; n++) {
            #pragma unroll
            for (int i = 0; i < 4; i++) {
                int row = m0 + wm * 128 + m * 16 + kc * 4 + i;
                int col = n0 + wn * 64 + n * 16 + r16;
                if (col < Nact) {
                    float v = acc[m][n][i];
                    if (EPI == 0) {
                        v += bias[col];
                        v = v / (1.0f + __expf(-v));
                    } else {
                        v *= __bfloat162float(U[(size_t)row * ldu + col]);
                    }
                    Cb[(size_t)row * ldc + col] = __float2bfloat16(v);
                }
            }
        }
    }
    #undef FRAG
    #undef STAGE_A
    #undef STAGE_B
}

extern "C" void kernel_launch(void* const* d_in, const int* in_sizes, int n_in,
                              void* d_out, int out_size, void* d_ws, size_t ws_size,
                              hipStream_t stream) {
    const float* x     = (const float*)d_in[0];
    const float* msin  = (const float*)d_in[1];
    const float* mcos  = (const float*)d_in[2];
    const int*   mask  = (const int*)d_in[3];
    const float* lnw   = (const float*)d_in[4];
    const float* lnb   = (const float*)d_in[5];
    const float* Wh    = (const float*)d_in[6];
    const float* bh    = (const float*)d_in[7];
    const float* gamma = (const float*)d_in[8];
    const float* beta  = (const float*)d_in[9];
    const float* Wo    = (const float*)d_in[10];
    const float* bo    = (const float*)d_in[11];
    float* out = (float*)d_out;
    char* ws = (char*)d_ws;

    __hip_bfloat16* xn  = (__hip_bfloat16*)(ws + OFF_XN);
    __hip_bfloat16* WhT = (__hip_bfloat16*)(ws + OFF_WHT);
    __hip_bfloat16* WoT = (__hip_bfloat16*)(ws + OFF_WOT);
    __hip_bfloat16* uv  = (__hip_bfloat16*)(ws + OFF_UV);
    __hip_bfloat16* q   = (__hip_bfloat16*)(ws + OFF_Q);
    __hip_bfloat16* k   = (__hip_bfloat16*)(ws + OFF_K);
    __hip_bfloat16* Vt  = (__hip_bfloat16*)(ws + OFF_VT);
    __hip_bfloat16* P   = (__hip_bfloat16*)(ws + OFF_P);
    __hip_bfloat16* hu  = (__hip_bfloat16*)(ws + OFF_HU);

    // 1. LayerNorm -> xn (bf16)
    ln_kernel<<<TOK, 256, 0, stream>>>(x, lnw, lnb, xn);

    // 2. weight transpose/convert (WhT zero-padded to 2304 rows)
    cvt_kernel<<<(NHIDP * DIMC + DIMC * HID + 255) / 256, 256, 0, stream>>>(Wh, Wo, WhT, WoT);

    // 3. GEMM1: uv = silu(xn @ Wh + bh)   [16384 x 2176(pad 2304) x 512]
    gemm256<0, 0><<<dim3(TOK / 256, NHIDP / 256, 1), 512, 0, stream>>>(
        xn, DIMC, 0, WhT, DIMC, 0, DIMC, NHID, bh,
        nullptr, 0, 0, uv, NHID, 0);

    // 4. q/k rotary, masked keys zeroed
    qkrot_kernel<<<TOK / 4, 256, 0, stream>>>(uv, msin, mcos, mask, gamma, beta, q, k);

    // 5. V transpose per batch
    vt_kernel<<<dim3(SEQ / 64, HID / 64, BATCH), 256, 0, stream>>>(uv, Vt);

    // 6. P = relu(q @ k^T)^2 / 32768   per batch [2048 x 2048 x 128]
    gemm_small<1><<<dim3(SEQ / 128, SEQ / 128, BATCH), 256, 0, stream>>>(
        q, QKD, (long long)SEQ * QKD, k, QKD, (long long)SEQ * QKD, QKD,
        P, SEQ, (long long)SEQ * SEQ);

    // 7. hu = (P @ V) * u   per batch [2048 x 1024 x 2048], batch ~ XCD
    gemm256<2, 1><<<dim3(SEQ / 256, HID / 256, BATCH), 512, 0, stream>>>(
        P, SEQ, (long long)SEQ * SEQ, Vt, SEQ, (long long)HID * SEQ, SEQ, HID, nullptr,
        uv, NHID, (long long)SEQ * NHID, hu, HID, (long long)SEQ * HID);

    // 8. out = hu @ Wo + bo + x   [16384 x 512 x 1024]
    gemm8p_final<<<dim3(TOK / 256, DIMC / 128), 512, 0, stream>>>(
        hu, HID, WoT, HID, HID, bo, x, DIMC, out, DIMC);
}